// Round 1
// baseline (1195.525 us; speedup 1.0000x reference)
//
#include <hip/hip_runtime.h>

static constexpr int   N_NODES = 50000;
static constexpr int   N_EDGES = 600000;
static constexpr int   D       = 128;
static constexpr float ALPHA   = 0.1f;
static constexpr float BETA    = 0.22314355131420976f;  // log(1.25)

// ---------------- degree count (edge-parallel atomics) ----------------
__global__ void deg_kernel(const int* __restrict__ dst, float* __restrict__ deg) {
    int e = blockIdx.x * blockDim.x + threadIdx.x;
    if (e < N_EDGES) atomicAdd(&deg[dst[e]], 1.0f);
}

// ---------------- norm = rsqrt(max(deg,1)) in place ----------------
__global__ void norm_kernel(float* __restrict__ deg_norm) {
    int i = blockIdx.x * blockDim.x + threadIdx.x;
    if (i < N_NODES) deg_norm[i] = rsqrtf(fmaxf(deg_norm[i], 1.0f));
}

// ---------------- scatter: agg[dst] += feat[src] * norm[src] ----------------
// 32 threads per edge, float4 per thread (4 atomics)
__global__ void scatter_kernel(const float* __restrict__ feat,
                               const int* __restrict__ src,
                               const int* __restrict__ dst,
                               const float* __restrict__ norm,
                               float* __restrict__ agg) {
    long long tid = (long long)blockIdx.x * blockDim.x + threadIdx.x;
    int e    = (int)(tid >> 5);
    int lane = (int)(tid & 31);
    if (e >= N_EDGES) return;
    int s = src[e];
    int d = dst[e];
    float ns = norm[s];
    const float4 v = *reinterpret_cast<const float4*>(feat + (size_t)s * D + lane * 4);
    float* base = agg + (size_t)d * D + lane * 4;
    atomicAdd(base + 0, v.x * ns);
    atomicAdd(base + 1, v.y * ns);
    atomicAdd(base + 2, v.z * ns);
    atomicAdd(base + 3, v.w * ns);
}

// ---------------- fused epilogue + GEMM ----------------
// per block: 16 rows. h = agg*norm*(1-a) + feat_0*a  built in LDS,
// W1 (64KB) in LDS, out = (1-b)*h + b*(h@W) + bias written in place over agg.
static constexpr int ROWS_PER_BLOCK = 16;

__global__ __launch_bounds__(256) void final_kernel(
    const float* __restrict__ feat_0,
    const float* __restrict__ W,
    const float* __restrict__ bias,
    const float* __restrict__ norm,
    float* __restrict__ out)   // enters holding agg, exits holding rst
{
    __shared__ float w_sh[D * D];              // 64 KB
    __shared__ float h_sh[ROWS_PER_BLOCK * D]; // 8 KB

    const int t    = threadIdx.x;
    const int row0 = blockIdx.x * ROWS_PER_BLOCK;

    // load W: 16384 floats / 256 threads = 16 float4 each, coalesced
    #pragma unroll
    for (int i = 0; i < 16; ++i) {
        int idx = (i * 256 + t) * 4;
        *reinterpret_cast<float4*>(&w_sh[idx]) =
            *reinterpret_cast<const float4*>(&W[idx]);
    }

    // build h tile in LDS: 2048 floats / 256 threads = 2 float4 each
    #pragma unroll
    for (int i = 0; i < 2; ++i) {
        int idx  = (i * 256 + t) * 4;          // 0..2044 step 4
        int r    = idx >> 7;                   // local row
        int c    = idx & 127;
        int node = row0 + r;
        float nm = norm[node];
        float4 a  = *reinterpret_cast<const float4*>(out    + (size_t)node * D + c);
        float4 f0 = *reinterpret_cast<const float4*>(feat_0 + (size_t)node * D + c);
        float4 h;
        h.x = a.x * nm * (1.0f - ALPHA) + f0.x * ALPHA;
        h.y = a.y * nm * (1.0f - ALPHA) + f0.y * ALPHA;
        h.z = a.z * nm * (1.0f - ALPHA) + f0.z * ALPHA;
        h.w = a.w * nm * (1.0f - ALPHA) + f0.w * ALPHA;
        *reinterpret_cast<float4*>(&h_sh[idx]) = h;
    }
    __syncthreads();

    // each thread: column `col`, rows rbase..rbase+7
    const int col   = t & 127;
    const int rbase = (t >> 7) * 8;   // 0 or 8

    float acc[8] = {0.f, 0.f, 0.f, 0.f, 0.f, 0.f, 0.f, 0.f};
    #pragma unroll 4
    for (int k = 0; k < D; ++k) {
        float w = w_sh[k * D + col];
        #pragma unroll
        for (int j = 0; j < 8; ++j)
            acc[j] += h_sh[(rbase + j) * D + k] * w;
    }

    const float b = bias[col];
    #pragma unroll
    for (int j = 0; j < 8; ++j) {
        int node = row0 + rbase + j;
        out[(size_t)node * D + col] =
            (1.0f - BETA) * h_sh[(rbase + j) * D + col] + BETA * acc[j] + b;
    }
}

extern "C" void kernel_launch(void* const* d_in, const int* in_sizes, int n_in,
                              void* d_out, int out_size, void* d_ws, size_t ws_size,
                              hipStream_t stream) {
    const float* feat   = (const float*)d_in[0];
    const float* feat_0 = (const float*)d_in[1];
    const float* W      = (const float*)d_in[2];
    const float* bias   = (const float*)d_in[3];
    const int*   src    = (const int*)d_in[4];
    const int*   dst    = (const int*)d_in[5];
    float*       out    = (float*)d_out;

    float* norm = (float*)d_ws;  // N_NODES floats (deg then norm, in place)

    // zero the accumulators (ws + out are poisoned 0xAA before every call)
    hipMemsetAsync(norm, 0, (size_t)N_NODES * sizeof(float), stream);
    hipMemsetAsync(out,  0, (size_t)N_NODES * D * sizeof(float), stream);

    // 1) degree
    deg_kernel<<<(N_EDGES + 255) / 256, 256, 0, stream>>>(dst, norm);
    // 2) norm
    norm_kernel<<<(N_NODES + 255) / 256, 256, 0, stream>>>(norm);
    // 3) scatter-add: 32 lanes/edge
    {
        long long threads = (long long)N_EDGES * 32;
        int blocks = (int)((threads + 255) / 256);
        scatter_kernel<<<blocks, 256, 0, stream>>>(feat, src, dst, norm, out);
    }
    // 4) fused epilogue + GEMM (N_NODES/16 = 3125 blocks)
    final_kernel<<<N_NODES / ROWS_PER_BLOCK, 256, 0, stream>>>(
        feat_0, W, bias, norm, out);
}

// Round 4
// 401.390 us; speedup vs baseline: 2.9785x; 2.9785x over previous
//
#include <hip/hip_runtime.h>

static constexpr int   N_NODES = 50000;
static constexpr int   N_EDGES = 600000;
static constexpr int   D       = 128;
static constexpr float ALPHA   = 0.1f;
static constexpr float BETA    = 0.22314355131420976f;  // log(1.25)

// ================= CSR path =================

// degree histogram (int atomics)
__global__ void deg_kernel(const int* __restrict__ dst, int* __restrict__ deg) {
    int e = blockIdx.x * blockDim.x + threadIdx.x;
    if (e < N_EDGES) atomicAdd(&deg[dst[e]], 1);
}

// single 256-thread block: exclusive scan of deg -> row_start (and cursor copy),
// fused norm = rsqrt(max(deg,1))
__global__ __launch_bounds__(256) void scan_kernel(const int* __restrict__ deg,
                                                   int* __restrict__ row_start,
                                                   int* __restrict__ cursor,
                                                   float* __restrict__ norm) {
    __shared__ int partial[256];
    const int t     = threadIdx.x;
    const int CHUNK = (N_NODES + 255) / 256;   // 196
    const int begin = t * CHUNK;
    const int end   = min(begin + CHUNK, N_NODES);
    int sum = 0;
    for (int i = begin; i < end; ++i) sum += deg[i];
    partial[t] = sum;
    __syncthreads();
    for (int off = 1; off < 256; off <<= 1) {
        int v = (t >= off) ? partial[t - off] : 0;
        __syncthreads();
        partial[t] += v;
        __syncthreads();
    }
    int run = (t == 0) ? 0 : partial[t - 1];
    for (int i = begin; i < end; ++i) {
        int d = deg[i];
        row_start[i] = run;
        cursor[i]    = run;
        norm[i]      = rsqrtf(fmaxf((float)d, 1.0f));
        run += d;
    }
}

// CSR fill: csr[pos] = src, pos = cursor[dst]++ (cursor pre-init to row_start)
__global__ void fill_kernel(const int* __restrict__ src, const int* __restrict__ dst,
                            int* __restrict__ cursor, int* __restrict__ csr) {
    int e = blockIdx.x * blockDim.x + threadIdx.x;
    if (e < N_EDGES) {
        int d   = dst[e];
        int pos = atomicAdd(&cursor[d], 1);
        if (pos >= 0 && pos < N_EDGES) csr[pos] = src[e];  // defensive bound
    }
}

// gather: agg[n] = sum_{e: dst=n} feat[src_e] * norm[src_e]
// one wave (64 lanes) per node; each lane owns 2 columns (float2)
__global__ __launch_bounds__(256) void gather_kernel(
    const float* __restrict__ feat, const int* __restrict__ csr,
    const int* __restrict__ row_start, const int* __restrict__ deg,
    const float* __restrict__ norm, float* __restrict__ agg) {
    const int node = blockIdx.x * 4 + (threadIdx.x >> 6);
    const int lane = threadIdx.x & 63;
    if (node >= N_NODES) return;
    const int base = row_start[node];
    const int cnt  = deg[node];
    float2 acc = make_float2(0.f, 0.f);
    int j = 0;
    for (; j + 1 < cnt; j += 2) {
        int s0 = csr[base + j];
        int s1 = csr[base + j + 1];
        float n0 = norm[s0];
        float n1 = norm[s1];
        float2 v0 = *reinterpret_cast<const float2*>(feat + (size_t)s0 * D + lane * 2);
        float2 v1 = *reinterpret_cast<const float2*>(feat + (size_t)s1 * D + lane * 2);
        acc.x += v0.x * n0 + v1.x * n1;
        acc.y += v0.y * n0 + v1.y * n1;
    }
    if (j < cnt) {
        int s = csr[base + j];
        float n = norm[s];
        float2 v = *reinterpret_cast<const float2*>(feat + (size_t)s * D + lane * 2);
        acc.x += v.x * n;
        acc.y += v.y * n;
    }
    *reinterpret_cast<float2*>(agg + (size_t)node * D + lane * 2) = acc;
}

// ================= fallback path (atomic scatter, known-passing) =================

__global__ void degf_kernel(const int* __restrict__ dst, float* __restrict__ deg) {
    int e = blockIdx.x * blockDim.x + threadIdx.x;
    if (e < N_EDGES) atomicAdd(&deg[dst[e]], 1.0f);
}

__global__ void normf_kernel(float* __restrict__ deg_norm) {
    int i = blockIdx.x * blockDim.x + threadIdx.x;
    if (i < N_NODES) deg_norm[i] = rsqrtf(fmaxf(deg_norm[i], 1.0f));
}

__global__ void scatter_kernel(const float* __restrict__ feat,
                               const int* __restrict__ src,
                               const int* __restrict__ dst,
                               const float* __restrict__ norm,
                               float* __restrict__ agg) {
    long long tid = (long long)blockIdx.x * blockDim.x + threadIdx.x;
    int e    = (int)(tid >> 5);
    int lane = (int)(tid & 31);
    if (e >= N_EDGES) return;
    int s = src[e];
    int d = dst[e];
    float ns = norm[s];
    const float4 v = *reinterpret_cast<const float4*>(feat + (size_t)s * D + lane * 4);
    float* base = agg + (size_t)d * D + lane * 4;
    atomicAdd(base + 0, v.x * ns);
    atomicAdd(base + 1, v.y * ns);
    atomicAdd(base + 2, v.z * ns);
    atomicAdd(base + 3, v.w * ns);
}

// ================= fused epilogue + GEMM (shared by both paths) =================
static constexpr int ROWS_PER_BLOCK = 16;

__global__ __launch_bounds__(256) void final_kernel(
    const float* __restrict__ feat_0,
    const float* __restrict__ W,
    const float* __restrict__ bias,
    const float* __restrict__ norm,
    float* __restrict__ out)   // enters holding agg, exits holding rst
{
    __shared__ float w_sh[D * D];              // 64 KB
    __shared__ float h_sh[ROWS_PER_BLOCK * D]; // 8 KB

    const int t    = threadIdx.x;
    const int row0 = blockIdx.x * ROWS_PER_BLOCK;

    #pragma unroll
    for (int i = 0; i < 16; ++i) {
        int idx = (i * 256 + t) * 4;
        *reinterpret_cast<float4*>(&w_sh[idx]) =
            *reinterpret_cast<const float4*>(&W[idx]);
    }

    #pragma unroll
    for (int i = 0; i < 2; ++i) {
        int idx  = (i * 256 + t) * 4;
        int r    = idx >> 7;
        int c    = idx & 127;
        int node = row0 + r;
        float nm = norm[node];
        float4 a  = *reinterpret_cast<const float4*>(out    + (size_t)node * D + c);
        float4 f0 = *reinterpret_cast<const float4*>(feat_0 + (size_t)node * D + c);
        float4 h;
        h.x = a.x * nm * (1.0f - ALPHA) + f0.x * ALPHA;
        h.y = a.y * nm * (1.0f - ALPHA) + f0.y * ALPHA;
        h.z = a.z * nm * (1.0f - ALPHA) + f0.z * ALPHA;
        h.w = a.w * nm * (1.0f - ALPHA) + f0.w * ALPHA;
        *reinterpret_cast<float4*>(&h_sh[idx]) = h;
    }
    __syncthreads();

    const int col   = t & 127;
    const int rbase = (t >> 7) * 8;

    float acc[8] = {0.f, 0.f, 0.f, 0.f, 0.f, 0.f, 0.f, 0.f};
    #pragma unroll 4
    for (int k = 0; k < D; ++k) {
        float w = w_sh[k * D + col];
        #pragma unroll
        for (int j = 0; j < 8; ++j)
            acc[j] += h_sh[(rbase + j) * D + k] * w;
    }

    const float b = bias[col];
    #pragma unroll
    for (int j = 0; j < 8; ++j) {
        int node = row0 + rbase + j;
        out[(size_t)node * D + col] =
            (1.0f - BETA) * h_sh[(rbase + j) * D + col] + BETA * acc[j] + b;
    }
}

extern "C" void kernel_launch(void* const* d_in, const int* in_sizes, int n_in,
                              void* d_out, int out_size, void* d_ws, size_t ws_size,
                              hipStream_t stream) {
    const float* feat   = (const float*)d_in[0];
    const float* feat_0 = (const float*)d_in[1];
    const float* W      = (const float*)d_in[2];
    const float* bias   = (const float*)d_in[3];
    const int*   src    = (const int*)d_in[4];
    const int*   dst    = (const int*)d_in[5];
    float*       out    = (float*)d_out;

    const size_t csr_ws_needed =
        (size_t)N_NODES * 4 * 4 + (size_t)N_EDGES * 4;  // deg,norm,row_start,cursor + csr

    if (ws_size >= csr_ws_needed) {
        // -------- CSR gather path --------
        char* ws = (char*)d_ws;
        int*   deg       = (int*)ws;    ws += (size_t)N_NODES * 4;
        float* norm      = (float*)ws;  ws += (size_t)N_NODES * 4;
        int*   row_start = (int*)ws;    ws += (size_t)N_NODES * 4;
        int*   cursor    = (int*)ws;    ws += (size_t)N_NODES * 4;
        int*   csr       = (int*)ws;    ws += (size_t)N_EDGES * 4;

        hipMemsetAsync(deg, 0, (size_t)N_NODES * sizeof(int), stream);

        deg_kernel <<<(N_EDGES + 255) / 256, 256, 0, stream>>>(dst, deg);
        scan_kernel<<<1, 256, 0, stream>>>(deg, row_start, cursor, norm);
        fill_kernel<<<(N_EDGES + 255) / 256, 256, 0, stream>>>(src, dst, cursor, csr);
        gather_kernel<<<(N_NODES + 3) / 4, 256, 0, stream>>>(feat, csr, row_start, deg, norm, out);
        final_kernel<<<N_NODES / ROWS_PER_BLOCK, 256, 0, stream>>>(feat_0, W, bias, norm, out);
    } else {
        // -------- fallback: atomic scatter (round-1 structure) --------
        float* norm = (float*)d_ws;  // N_NODES floats

        hipMemsetAsync(norm, 0, (size_t)N_NODES * sizeof(float), stream);
        hipMemsetAsync(out,  0, (size_t)N_NODES * D * sizeof(float), stream);

        degf_kernel <<<(N_EDGES + 255) / 256, 256, 0, stream>>>(dst, norm);
        normf_kernel<<<(N_NODES + 255) / 256, 256, 0, stream>>>(norm);
        long long threads = (long long)N_EDGES * 32;
        int blocks = (int)((threads + 255) / 256);
        scatter_kernel<<<blocks, 256, 0, stream>>>(feat, src, dst, norm, out);
        final_kernel<<<N_NODES / ROWS_PER_BLOCK, 256, 0, stream>>>(feat_0, W, bias, norm, out);
    }
}

// Round 5
// 263.641 us; speedup vs baseline: 4.5347x; 1.5225x over previous
//
#include <hip/hip_runtime.h>

static constexpr int   N_NODES = 50000;
static constexpr int   N_EDGES = 600000;
static constexpr int   D       = 128;
static constexpr float ALPHA   = 0.1f;
static constexpr float BETA    = 0.22314355131420976f;  // log(1.25)

static constexpr int SCAN_TPB    = 256;
static constexpr int SCAN_BLOCKS = (N_NODES + SCAN_TPB - 1) / SCAN_TPB;  // 196

// ---------------- degree histogram (int atomics) ----------------
__global__ void deg_kernel(const int* __restrict__ dst, int* __restrict__ deg) {
    int e = blockIdx.x * blockDim.x + threadIdx.x;
    if (e < N_EDGES) atomicAdd(&deg[dst[e]], 1);
}

// ---------------- scan phase 1: per-block reduction ----------------
__global__ __launch_bounds__(SCAN_TPB) void partial_kernel(const int* __restrict__ deg,
                                                           int* __restrict__ blocksum) {
    __shared__ int sh[SCAN_TPB];
    const int t = threadIdx.x;
    const int i = blockIdx.x * SCAN_TPB + t;
    sh[t] = (i < N_NODES) ? deg[i] : 0;
    __syncthreads();
    for (int off = SCAN_TPB / 2; off > 0; off >>= 1) {
        if (t < off) sh[t] += sh[t + off];
        __syncthreads();
    }
    if (t == 0) blocksum[blockIdx.x] = sh[0];
}

// ---------------- scan phase 2: exclusive scan of block sums (1 block) ----------------
__global__ __launch_bounds__(SCAN_TPB) void scanblock_kernel(int* __restrict__ blocksum) {
    __shared__ int sh[SCAN_TPB];
    const int t = threadIdx.x;
    int v = (t < SCAN_BLOCKS) ? blocksum[t] : 0;
    sh[t] = v;
    __syncthreads();
    for (int off = 1; off < SCAN_TPB; off <<= 1) {
        int u = (t >= off) ? sh[t - off] : 0;
        __syncthreads();
        sh[t] += u;
        __syncthreads();
    }
    if (t < SCAN_BLOCKS) blocksum[t] = sh[t] - v;   // exclusive
}

// ---------------- scan phase 3: per-block exclusive scan + offset; fused norm ----------------
__global__ __launch_bounds__(SCAN_TPB) void finalscan_kernel(
    const int* __restrict__ deg, const int* __restrict__ blocksum,
    int* __restrict__ row_start, int* __restrict__ cursor, float* __restrict__ norm) {
    __shared__ int sh[SCAN_TPB];
    const int t = threadIdx.x;
    const int i = blockIdx.x * SCAN_TPB + t;
    int d = (i < N_NODES) ? deg[i] : 0;
    sh[t] = d;
    __syncthreads();
    for (int off = 1; off < SCAN_TPB; off <<= 1) {
        int u = (t >= off) ? sh[t - off] : 0;
        __syncthreads();
        sh[t] += u;
        __syncthreads();
    }
    if (i < N_NODES) {
        int pos = blocksum[blockIdx.x] + sh[t] - d;   // exclusive prefix
        row_start[i] = pos;
        cursor[i]    = pos;
        norm[i]      = rsqrtf(fmaxf((float)d, 1.0f));
    }
}

// ---------------- CSR fill: csr[pos] = src, pos = cursor[dst]++ ----------------
__global__ void fill_kernel(const int* __restrict__ src, const int* __restrict__ dst,
                            int* __restrict__ cursor, int* __restrict__ csr) {
    int e = blockIdx.x * blockDim.x + threadIdx.x;
    if (e < N_EDGES) {
        int d   = dst[e];
        int pos = atomicAdd(&cursor[d], 1);
        if (pos >= 0 && pos < N_EDGES) csr[pos] = src[e];  // defensive bound
    }
}

// ---------------- gather: agg[n] = sum_{e: dst=n} feat[src_e] * norm[src_e] ----------------
// one wave (64 lanes) per node; each lane owns 2 columns (float2)
__global__ __launch_bounds__(256) void gather_kernel(
    const float* __restrict__ feat, const int* __restrict__ csr,
    const int* __restrict__ row_start, const int* __restrict__ deg,
    const float* __restrict__ norm, float* __restrict__ agg) {
    const int node = blockIdx.x * 4 + (threadIdx.x >> 6);
    const int lane = threadIdx.x & 63;
    if (node >= N_NODES) return;
    const int base = row_start[node];
    const int cnt  = deg[node];
    float2 acc = make_float2(0.f, 0.f);
    int j = 0;
    for (; j + 1 < cnt; j += 2) {
        int s0 = csr[base + j];
        int s1 = csr[base + j + 1];
        float n0 = norm[s0];
        float n1 = norm[s1];
        float2 v0 = *reinterpret_cast<const float2*>(feat + (size_t)s0 * D + lane * 2);
        float2 v1 = *reinterpret_cast<const float2*>(feat + (size_t)s1 * D + lane * 2);
        acc.x += v0.x * n0 + v1.x * n1;
        acc.y += v0.y * n0 + v1.y * n1;
    }
    if (j < cnt) {
        int s = csr[base + j];
        float n = norm[s];
        float2 v = *reinterpret_cast<const float2*>(feat + (size_t)s * D + lane * 2);
        acc.x += v.x * n;
        acc.y += v.y * n;
    }
    *reinterpret_cast<float2*>(agg + (size_t)node * D + lane * 2) = acc;
}

// ---------------- fused epilogue + GEMM ----------------
static constexpr int ROWS_PER_BLOCK = 16;

__global__ __launch_bounds__(256) void final_kernel(
    const float* __restrict__ feat_0,
    const float* __restrict__ W,
    const float* __restrict__ bias,
    const float* __restrict__ norm,
    float* __restrict__ out)   // enters holding agg, exits holding rst
{
    __shared__ float w_sh[D * D];              // 64 KB
    __shared__ float h_sh[ROWS_PER_BLOCK * D]; // 8 KB

    const int t    = threadIdx.x;
    const int row0 = blockIdx.x * ROWS_PER_BLOCK;

    #pragma unroll
    for (int i = 0; i < 16; ++i) {
        int idx = (i * 256 + t) * 4;
        *reinterpret_cast<float4*>(&w_sh[idx]) =
            *reinterpret_cast<const float4*>(&W[idx]);
    }

    #pragma unroll
    for (int i = 0; i < 2; ++i) {
        int idx  = (i * 256 + t) * 4;
        int r    = idx >> 7;
        int c    = idx & 127;
        int node = row0 + r;
        float nm = norm[node];
        float4 a  = *reinterpret_cast<const float4*>(out    + (size_t)node * D + c);
        float4 f0 = *reinterpret_cast<const float4*>(feat_0 + (size_t)node * D + c);
        float4 h;
        h.x = a.x * nm * (1.0f - ALPHA) + f0.x * ALPHA;
        h.y = a.y * nm * (1.0f - ALPHA) + f0.y * ALPHA;
        h.z = a.z * nm * (1.0f - ALPHA) + f0.z * ALPHA;
        h.w = a.w * nm * (1.0f - ALPHA) + f0.w * ALPHA;
        *reinterpret_cast<float4*>(&h_sh[idx]) = h;
    }
    __syncthreads();

    const int col   = t & 127;
    const int rbase = (t >> 7) * 8;

    float acc[8] = {0.f, 0.f, 0.f, 0.f, 0.f, 0.f, 0.f, 0.f};
    #pragma unroll 4
    for (int k = 0; k < D; ++k) {
        float w = w_sh[k * D + col];
        #pragma unroll
        for (int j = 0; j < 8; ++j)
            acc[j] += h_sh[(rbase + j) * D + k] * w;
    }

    const float b = bias[col];
    #pragma unroll
    for (int j = 0; j < 8; ++j) {
        int node = row0 + rbase + j;
        out[(size_t)node * D + col] =
            (1.0f - BETA) * h_sh[(rbase + j) * D + col] + BETA * acc[j] + b;
    }
}

extern "C" void kernel_launch(void* const* d_in, const int* in_sizes, int n_in,
                              void* d_out, int out_size, void* d_ws, size_t ws_size,
                              hipStream_t stream) {
    const float* feat   = (const float*)d_in[0];
    const float* feat_0 = (const float*)d_in[1];
    const float* W      = (const float*)d_in[2];
    const float* bias   = (const float*)d_in[3];
    const int*   src    = (const int*)d_in[4];
    const int*   dst    = (const int*)d_in[5];
    float*       out    = (float*)d_out;

    // workspace layout (validated: CSR path ran in round 4 → ws_size is sufficient)
    char* ws = (char*)d_ws;
    int*   deg       = (int*)ws;    ws += (size_t)N_NODES * 4;
    float* norm      = (float*)ws;  ws += (size_t)N_NODES * 4;
    int*   row_start = (int*)ws;    ws += (size_t)N_NODES * 4;
    int*   cursor    = (int*)ws;    ws += (size_t)N_NODES * 4;
    int*   blocksum  = (int*)ws;    ws += (size_t)SCAN_TPB * 4;
    int*   csr       = (int*)ws;    ws += (size_t)N_EDGES * 4;

    hipMemsetAsync(deg, 0, (size_t)N_NODES * sizeof(int), stream);

    deg_kernel<<<(N_EDGES + 255) / 256, 256, 0, stream>>>(dst, deg);

    partial_kernel  <<<SCAN_BLOCKS, SCAN_TPB, 0, stream>>>(deg, blocksum);
    scanblock_kernel<<<1,           SCAN_TPB, 0, stream>>>(blocksum);
    finalscan_kernel<<<SCAN_BLOCKS, SCAN_TPB, 0, stream>>>(deg, blocksum,
                                                           row_start, cursor, norm);

    fill_kernel<<<(N_EDGES + 255) / 256, 256, 0, stream>>>(src, dst, cursor, csr);
    gather_kernel<<<(N_NODES + 3) / 4, 256, 0, stream>>>(feat, csr, row_start, deg, norm, out);
    final_kernel<<<N_NODES / ROWS_PER_BLOCK, 256, 0, stream>>>(feat_0, W, bias, norm, out);
}